// Round 9
// baseline (496.751 us; speedup 1.0000x reference)
//
#include <hip/hip_runtime.h>
#include <math.h>

// Problem constants (setup_inputs: N=32, C=1, W=512, L=512)
#define WD 512          // image / detector width
#define PF 1024         // FFT pad length
#define LH2 1028        // shifted ramp-kernel table length

// Workspace layout (float offsets). ws bytes: 16 KB + 33.55 MB table.
#define OFF_H2 0        // 1028 floats
#define OFF_ANG 2048    // 512 x float4 (chw, shw, wB, iA-bits)
#define OFF_PK 4096     // packed fp16 sinogram: [g][l][s] uint4 (4 imgs x (y[s],y[s+1]))

#define GOFF 107        // LDS slot = detector_index + GOFF (guards absorb out-of-circle idx)
#define GSLOTS 726      // covers idx in [-107, 618]

typedef __fp16 half2_t __attribute__((ext_vector_type(2)));
typedef _Float16 f16x8 __attribute__((ext_vector_type(8)));
typedef float f32x4v __attribute__((ext_vector_type(4)));

__device__ __forceinline__ half2_t pkh(float a, float b) {
  return __builtin_amdgcn_cvt_pkrtz(a, b);   // v_cvt_pkrtz_f16_f32
}
__device__ __forceinline__ unsigned pkbits(float a, float b) {
  return __builtin_bit_cast(unsigned, pkh(a, b));
}
__device__ __forceinline__ float dot2f(unsigned tapbits, half2_t w, float c) {
  half2_t tp = __builtin_bit_cast(half2_t, tapbits);
  return __builtin_amdgcn_fdot2(tp, w, c, false);   // v_dot2_f32_f16
}

__device__ __forceinline__ float t2(int p) {
  return (float)(-1.0 + 2.0 * (double)p / (double)(WD - 1));
}

// ---------------------------------------------------------------------------
// Setup: h2[i] = h[(i-512) & 1023] via v_cos (arg in REVOLUTIONS). UNCHANGED.
// ---------------------------------------------------------------------------
__global__ void setup_kernel(const float* __restrict__ theta,
                             float* __restrict__ ws, int L) {
  int gid = blockIdx.x * blockDim.x + threadIdx.x;
  if (gid < LH2) {
    int dd = gid - (PF / 2);
    if (dd < 0) dd = -dd;
    float acc = 0.f;
    for (int k = 0; k < PF; ++k) {
      int kk = (k <= PF / 2) ? k : (PF - k);
      float filt = 2.f * (float)kk * (1.f / (float)PF);
      int m = (k * dd) & (PF - 1);            // phase in [0,1) revolutions
#if __has_builtin(__builtin_amdgcn_cosf)
      float cv = __builtin_amdgcn_cosf((float)m * (1.f / (float)PF));
#else
      float cv = cosf((float)m * (6.28318530717958647692f / (float)PF));
#endif
      acc = fmaf(filt, cv, acc);
    }
    ws[OFF_H2 + gid] = acc * (1.f / (float)PF);
  } else if (gid < LH2 + L) {
    int l = gid - LH2;
    double rad = (double)theta[l] * 0.017453292519943295;
    const float hw = 0.5f * (float)(WD - 1);
    float cx = (float)l * (float)((double)(WD - 1) / (double)(L - 1));
    float c0 = floorf(cx);
    float wc = cx - c0;
    int ia = (int)c0;
    float ok = (ia + 1 <= WD - 1) ? 1.f : 0.f;
    float4 a;
    a.x = (float)cos(rad) * hw;
    a.y = (float)sin(rad) * hw;
    a.z = wc * ok;                       // wB (0 when L==WD: cx = l exactly)
    a.w = __int_as_float(ia);
    ((float4*)(ws + OFF_ANG))[l] = a;
  }
}

// ---------------------------------------------------------------------------
// Filter v6: fp16 MFMA GEMM, 4 IMAGES PER BLOCK -> full-line uint4 stores.
// R8 post-mortem: the ~60us filter floor was the store path — one dword per
// entry at stride 16 B, with the 4 image-lanes of every 64 B pk line written
// by 4 DIFFERENT blocks on different XCDs (partial-line RMW + false sharing
// across non-coherent L2s ~ 8x the useful write traffic). v6 computes all 4
// images of a group in ONE block: every pk uint4 entry is assembled
// in-register by exactly one lane, and each lane stores 4 consecutive
// entries = one full 64 B line (4x global_store_dwordx4, single writer).
//   GEMM: M=512 (full s, in-block -> no cross-block s+1 coupling),
//   N=64 (4 img x 16 l), K=512. Grid 32 slabs x 8 groups = 256 blocks,
//   512 thr (8 waves, 2/SIMD — same occupancy as v5). Wave wv owns
//   s in [wv*64, wv*64+64): 4 mf x 4 nf frags; nf = image.
//   A (Toeplitz, v5-proven): 8 shift-copies of fp16-reversed h2, stride
//   2064 B; copy p=a0&7 at offset a0&~7 -> aligned ds_read_b128;
//   a0 = 515 - s + k0, s = wv*64+mf*16+(lane&15), k0 = kt*32+(lane>>4)*8.
//   B: c = img*16+lcol; Bl[c][k] ushort at c*80+k*2 (dbuf 2x5120 B);
//   stage: thread t: c=t&63, rows (t>>6)*4+r; one barrier per kt (v5 dbuf).
//   Epilogue (all in-register): lane holds v[0..3] = y[s0..s0+3] per img
//   (D row = (lane>>4)*4+reg [m89]); entry dwords d0..d2 from own pairs,
//   d3 hi = next v0 via __shfl rot16 ((lane+16)&63: lane<48 -> same-mf
//   q+1; lane>=48 -> mf+1 q0) or cross-wave LDS xch (wv boundary) or 0
//   (s=511). Accumulation order identical to v5 -> pk bit-identical.
// ---------------------------------------------------------------------------
__global__ __launch_bounds__(512, 2) void filter_mfma(
    const float* __restrict__ x, const float* __restrict__ ws,
    unsigned char* __restrict__ pk) {
  __shared__ __align__(16) unsigned char smem[28800];
  // [0,16512)      h2 copies: 8 x 1032 ushorts (2064 B stride)
  // [16512,26752)  Bl[2]: 2 x (64 cols x 40 ushorts, 80 B rows)
  // [26752,28800)  xch: [8 wv][4 img][16 lcol] f32 (wave-boundary y values)
  unsigned short* const h2cs = (unsigned short*)smem;
  unsigned char* const bls = smem + 16512;
  float* const xch = (float*)(smem + 26752);

  const int t = threadIdx.x;
  const int slab = blockIdx.x;               // l-slab [slab*16, +16)
  const int g = blockIdx.y;                  // image group (4 imgs)
  const int lane = t & 63, wv = t >> 6;      // 8 waves

  // h2cs[p][i] = fp16(h2rev[i+p]) = fp16(h2[1027-i-p]); OOB -> 0 (never read)
  for (int u = t; u < 8192; u += 512) {
    int p = u >> 10, i = u & 1023;
    int gi = 1027 - i - p;
    float v = (gi >= 0) ? ws[OFF_H2 + gi] : 0.f;
    h2cs[p * 1032 + i] = __builtin_bit_cast(unsigned short, (_Float16)v);
  }

  // B staging role: c = lane (img*16+lcol), k-quad = wv (rows wv*4+r per kt)
  const int c = lane;
  const int simg = c >> 4, slcol = c & 15;
  const float* __restrict__ xs =
      x + (size_t)(g * 4 + simg) * (WD * WD) + slab * 16 + slcol;

  const int aBase = 515 - (wv << 6) - (lane & 15) + ((lane >> 4) << 3);
  const int bq = lane >> 4;

  f32x4v acc[4][4];                          // [mf][img]
#pragma unroll
  for (int i = 0; i < 4; ++i)
#pragma unroll
    for (int j = 0; j < 4; ++j) acc[i][j] = (f32x4v)0.f;

  float pf[2][4];
  {                                          // preload kt = 0 tile
    const float* xb = xs + (size_t)(wv * 4) * WD;
#pragma unroll
    for (int r = 0; r < 4; ++r) pf[0][r] = xb[r * WD];
  }

#pragma unroll
  for (int kt = 0; kt < 16; ++kt) {
    const int cur = kt & 1;
    if (kt < 15) {                           // issue next tile's loads early
      const float* xb = xs + (size_t)((kt + 1) * 32 + wv * 4) * WD;
#pragma unroll
      for (int r = 0; r < 4; ++r) pf[cur ^ 1][r] = xb[r * WD];
    }
    unsigned char* bl = bls + cur * 5120;
    *(unsigned*)(bl + c * 80 + wv * 8) = pkbits(pf[cur][0], pf[cur][1]);
    *(unsigned*)(bl + c * 80 + wv * 8 + 4) = pkbits(pf[cur][2], pf[cur][3]);
    __syncthreads();                         // Bl[cur] ready (ONE barrier/kt)
    f16x8 bf[4];
#pragma unroll
    for (int nf = 0; nf < 4; ++nf)
      bf[nf] = *(const f16x8*)(bl + ((nf << 4) + (lane & 15)) * 80 + bq * 16);
    const int aK = aBase + (kt << 5);
#pragma unroll
    for (int mf = 0; mf < 4; ++mf) {
      int a0 = aK - (mf << 4);
      f16x8 af = *(const f16x8*)(smem + (a0 & 7) * 2064 + ((a0 & ~7) << 1));
#pragma unroll
      for (int nf = 0; nf < 4; ++nf)
        acc[mf][nf] = __builtin_amdgcn_mfma_f32_16x16x32_f16(af, bf[nf],
                                                             acc[mf][nf], 0, 0, 0);
    }
  }

  // Cross-wave exchange: first-s value (mf=0, q=0, reg=0) per img per lcol.
  if (lane < 16) {
#pragma unroll
    for (int nf = 0; nf < 4; ++nf)
      xch[(wv * 4 + nf) * 16 + lane] = acc[0][nf][0];
  }
  __syncthreads();

  // Epilogue: per (mf, img): d0..d3 entry dwords; d3 hi = next v0.
  unsigned char* __restrict__ pg = pk + (size_t)g * (512u * 512u * 16u);
  const int lout = slab * 16 + (lane & 15);
  float rot[4][4];                           // rot16 of v0[mf][img]
#pragma unroll
  for (int mf = 0; mf < 4; ++mf)
#pragma unroll
    for (int im = 0; im < 4; ++im)
      rot[mf][im] = __shfl(acc[mf][im][0], (lane + 16) & 63);
  float xv[4];
#pragma unroll
  for (int im = 0; im < 4; ++im)
    xv[im] = (wv < 7) ? xch[((wv + 1) * 4 + im) * 16 + (lane & 15)] : 0.f;

#pragma unroll
  for (int mf = 0; mf < 4; ++mf) {
    uint4 e[4];
#pragma unroll
    for (int im = 0; im < 4; ++im) {
      f32x4v v = acc[mf][im];
      float nx = (lane < 48) ? rot[mf][im]
                             : (mf < 3 ? rot[mf + 1][im] : xv[im]);
      (&e[0].x)[im] = pkbits(v[0], v[1]);
      (&e[1].x)[im] = pkbits(v[1], v[2]);
      (&e[2].x)[im] = pkbits(v[2], v[3]);
      (&e[3].x)[im] = pkbits(v[3], nx);
    }
    int s0 = (wv << 6) + (mf << 4) + ((lane >> 4) << 2);
    unsigned char* ep = pg + ((size_t)lout * 512 + (size_t)s0) * 16;
    *(uint4*)(ep) = e[0];                    // 64 B line fully written by
    *(uint4*)(ep + 16) = e[1];               // this single lane
    *(uint4*)(ep + 32) = e[2];
    *(uint4*)(ep + 48) = e[3];
  }
}

// ---------------------------------------------------------------------------
// Backprojection v6 (R2-exact, best measured 422-433 us): 1024-thread blocks,
// 64x64 px x 4 imgs, TWO angles per LDS round, ONE barrier per 2 angles,
// ds_write staging. R3/R4/R5: gload_lds neutral, barrier-free -22%,
// barrier-halving -6% -> this structure's plateau; keep verbatim.
// R1 lesson: vector-memory gathers are line-serial (~26cy) — LDS only.
// ---------------------------------------------------------------------------
__device__ __forceinline__ uint4 blend4(uint4 a, uint4 b, float wA, float wB) {
  unsigned r[4];
  const unsigned* pa = &a.x; const unsigned* pb = &b.x;
#pragma unroll
  for (int i = 0; i < 4; ++i) {
    half2_t ha = __builtin_bit_cast(half2_t, pa[i]);
    half2_t hb = __builtin_bit_cast(half2_t, pb[i]);
    r[i] = pkbits(fmaf((float)ha.x, wA, (float)hb.x * wB),
                  fmaf((float)ha.y, wA, (float)hb.y * wB));
  }
  return make_uint4(r[0], r[1], r[2], r[3]);
}

__device__ __forceinline__ void loadrow(const unsigned char* gb, float4 a, int s,
                                        uint4& v) {
  int ia = __float_as_int(a.w);
  v = *(const uint4*)(gb + (size_t)ia * (512 * 16) + (size_t)s * 16);
  float wB = a.z;
  if (wB != 0.f) {                       // generic angle interp (never taken, L==WD)
    int ib = ia + 1 < 511 ? ia + 1 : 511;
    uint4 u = *(const uint4*)(gb + (size_t)ib * (512 * 16) + (size_t)s * 16);
    v = blend4(v, u, 1.f - wB, wB);
  }
}

__device__ __forceinline__ void accum_angle(const uint4* __restrict__ br,
                                            float4 a, float tiv,
                                            const float* __restrict__ tjv,
                                            float hw, float acc[4][4]) {
  const float chw = a.x, shw = a.y;
  float bi = fmaf(tiv, -shw, hw);
#pragma unroll
  for (int dj = 0; dj < 4; ++dj) {
    float ry = fmaf(tjv[dj], chw, bi);
    int idx = (int)ry;                   // trunc; OOB lands in zero guards
    float w1 = ry - (float)idx;
    half2_t wpk = pkh(1.f - w1, w1);
    uint4 q = br[idx + GOFF];            // one ds_read_b128 serves 4 images
    acc[dj][0] = dot2f(q.x, wpk, acc[dj][0]);
    acc[dj][1] = dot2f(q.y, wpk, acc[dj][1]);
    acc[dj][2] = dot2f(q.z, wpk, acc[dj][2]);
    acc[dj][3] = dot2f(q.w, wpk, acc[dj][3]);
  }
}

__global__ __launch_bounds__(1024, 8) void backproj_kernel(
    const float* __restrict__ ws, const unsigned char* __restrict__ pk,
    float* __restrict__ out, int L) {
  __shared__ __align__(16) uint4 buf[2][2][GSLOTS];   // [round parity][angle][slot]
  const int t = threadIdx.x;
  const int tx = t & 15, ty = t >> 4;        // ty: 0..63 (full i of tile)
  const int j0 = (blockIdx.x & 7) << 6;
  const int i0 = (blockIdx.x >> 3) << 6;
  const int g = blockIdx.y;
  const int n0 = g << 2;

  const float tiv = t2(i0 + ty);
  float tjv[4];
#pragma unroll
  for (int a = 0; a < 4; ++a) tjv[a] = t2(j0 + tx + 16 * a);

  // Corner-tile skip: entire 64x64 tile outside the circle -> zeros, no compute.
  {
    float il = t2(i0), ih = t2(i0 + 63);
    float jl = t2(j0), jh = t2(j0 + 63);
    float mi = (il <= 0.f && ih >= 0.f) ? 0.f : fminf(fabsf(il), fabsf(ih));
    float mj = (jl <= 0.f && jh >= 0.f) ? 0.f : fminf(fabsf(jl), fabsf(jh));
    if (mi * mi + mj * mj > 1.f) {
#pragma unroll
      for (int k = 0; k < 4; ++k) {
        float* ob = out + (size_t)(n0 + k) * WD * WD + (size_t)(i0 + ty) * WD;
#pragma unroll
        for (int dj = 0; dj < 4; ++dj) ob[j0 + tx + 16 * dj] = 0.f;
      }
      return;
    }
  }

  const float4* __restrict__ angp = (const float4*)(ws + OFF_ANG);
  const unsigned char* gb = pk + (size_t)g * (512 * 512 * 16);

  for (int s = t; s < 2 * 2 * GSLOTS; s += 1024)
    ((uint4*)buf)[s] = make_uint4(0u, 0u, 0u, 0u);
  __syncthreads();                       // guards visible before first staging

  const float hw = 0.5f * (float)(WD - 1);
  float acc[4][4] = {};                  // [dj][img]

  const int sA = t & 511;                // staged slot
  const int p = t >> 9;                  // which of the round's 2 angles we stage

  float4 aA = angp[0];
  float4 aB = angp[L > 1 ? 1 : 0];
  uint4 v;
  loadrow(gb, p ? aB : aA, sA, v);

  const int rounds = (L + 1) >> 1;
  for (int r = 0; r < rounds; ++r) {
    const int rp = r & 1;
    buf[rp][p][GOFF + sA] = v;           // 1 ds_write_b128, conflict-free
    int na = 2 * r + 2, nb = 2 * r + 3;
    float4 aA2 = angp[na < L ? na : L - 1];
    float4 aB2 = angp[nb < L ? nb : L - 1];
    if (r + 1 < rounds) loadrow(gb, p ? aB2 : aA2, sA, v);   // overlap compute
    __syncthreads();                     // ONE barrier per 2 angles

    accum_angle(&buf[rp][0][0], aA, tiv, tjv, hw, acc);
    if (2 * r + 1 < L)
      accum_angle(&buf[rp][1][0], aB, tiv, tjv, hw, acc);
    aA = aA2; aB = aB2;
  }

  const float scale = (float)(3.14159265358979323846 / (2.0 * (double)L));
#pragma unroll
  for (int k = 0; k < 4; ++k) {
    float* ob = out + (size_t)(n0 + k) * WD * WD + (size_t)(i0 + ty) * WD;
#pragma unroll
    for (int dj = 0; dj < 4; ++dj) {
      float rr = tiv * tiv + tjv[dj] * tjv[dj];
      ob[j0 + tx + 16 * dj] = (rr <= 1.f) ? acc[dj][k] * scale : 0.f;
    }
  }
}

extern "C" void kernel_launch(void* const* d_in, const int* in_sizes, int n_in,
                              void* d_out, int out_size, void* d_ws, size_t ws_size,
                              hipStream_t stream) {
  const float* x = (const float*)d_in[0];
  const float* theta = (const float*)d_in[1];
  float* out = (float*)d_out;
  float* ws = (float*)d_ws;
  int L = in_sizes[1];                       // 512
  int NC = in_sizes[0] / (WD * WD);          // 32
  unsigned char* pk = (unsigned char*)(ws + OFF_PK);

  int nset = LH2 + L;
  hipLaunchKernelGGL(setup_kernel, dim3((nset + 255) / 256), dim3(256), 0, stream,
                     theta, ws, L);
  hipLaunchKernelGGL(filter_mfma, dim3(32, NC / 4), dim3(512), 0, stream,
                     x, ws, pk);
  hipLaunchKernelGGL(backproj_kernel, dim3(64, NC / 4), dim3(1024), 0, stream,
                     ws, pk, out, L);
}